// Round 3
// baseline (103.475 us; speedup 1.0000x reference)
//
#include <hip/hip_runtime.h>
#include <stdint.h>

// S=512, B=64, H=8, K=12, P=9, L=137, T=4096, THRESH=4
// Workspace layout (u32 units):
//   [0, 65536)        packed ram tables: 128 u32 per hb (hb-major)  = 256 KB
//   [65536, 66560)    packed token rows: 512 u64                    = 4 KB
//   [66560, 74752)    parity bits: [hb][chunk(8)][2] u32            = 32 KB
//   [74752, 140288)   bit-permuted tables (nr==0, 4<=nk<=7 only):
//                     128 u32 per hb, linear index (qidx<<nk)|kidx  = 256 KB
#define WS_TABLE  0
#define WS_TOKROW 65536
#define WS_PAR    66560
#define WS_TPERM  74752

// ---- Kernel 0: pack ram bits + token rows; build permuted table per hb ----
__global__ __launch_bounds__(256) void softram_pack_kernel(
    const int* __restrict__ tokens,   // (512, 64)
    const int* __restrict__ conn,     // (8, 64, 12)
    const float* __restrict__ ram,    // (8, 64, 4096) values in {0,1}
    uint32_t* __restrict__ ws)
{
    __shared__ uint32_t tab[128];
    const int tid = threadIdx.x, lane = tid & 63, w = tid >> 6;
    if (blockIdx.x < 512) {
        const int hb = blockIdx.x;
        const float* ramp = ram + (size_t)hb * 4096;
        uint32_t* tp = ws + WS_TABLE + hb * 128;
        #pragma unroll
        for (int c = 0; c < 16; ++c) {
            float v = ramp[c * 256 + tid];
            unsigned long long m = __ballot(v > 0.5f);
            if (lane == 0) {
                uint32_t lo = (uint32_t)m, hi = (uint32_t)(m >> 32);
                tp[c * 8 + w * 2]      = lo;
                tp[c * 8 + w * 2 + 1]  = hi;
                tab[c * 8 + w * 2]     = lo;
                tab[c * 8 + w * 2 + 1] = hi;
            }
        }
        __syncthreads();
        // classify conn for this hb
        int ckv[12];
        #pragma unroll
        for (int k = 0; k < 12; ++k) ckv[k] = conn[hb * 12 + k];
        int nr = 0, nk = 0;
        #pragma unroll
        for (int k = 0; k < 12; ++k) {
            if (ckv[k] >= 128) ++nr;
            else if (ckv[k] >= 64) ++nk;
        }
        if (!(nr == 0 && nk >= 4 && nk <= 7)) return;   // block-uniform
        // cumulative scatter masks of the low-m kidx bits (m = 1..4)
        uint32_t sk1 = 0, sk2 = 0, sk3 = 0, sk4 = 0;
        {
            int nkc = 0; uint32_t cur = 0;
            #pragma unroll
            for (int k = 0; k < 12; ++k) {
                if (ckv[k] >= 64) {                      // k-type (nr==0)
                    if (nkc < 4) {
                        cur |= 1u << k;
                        if      (nkc == 0) sk1 = cur;
                        else if (nkc == 1) sk2 = cur;
                        else if (nkc == 2) sk3 = cur;
                        else               sk4 = cur;
                    }
                    ++nkc;
                }
            }
        }
        // thread builds 16 consecutive bits of the permuted table:
        // linear index l = (qidx << nk) | kidx ; bit = T[scatter(qidx,kidx)]
        const int l0 = tid * 16;
        const int kidx0 = l0 & ((1 << nk) - 1);
        const int qidx0 = l0 >> nk;
        uint32_t a = 0;
        {
            int nqc = 0, nkc = 0;
            #pragma unroll
            for (int k = 0; k < 12; ++k) {
                int cv = ckv[k];
                if (cv < 64) { a |= (uint32_t)((qidx0 >> nqc) & 1) << k; ++nqc; }
                else         { a |= (uint32_t)((kidx0 >> nkc) & 1) << k; ++nkc; }
            }
        }
        // Gray-style walk: l -> l+1 flips low (ctz+1) kidx bits (nk>=4 so the
        // low 4 bits of l are kidx bits; compile-time mask selection)
        uint32_t acc = (tab[a >> 5] >> (a & 31)) & 1u;
        #define TPSTEP(b, skm) { a ^= (skm); acc |= ((tab[a >> 5] >> (a & 31)) & 1u) << (b); }
        TPSTEP(1,  sk1) TPSTEP(2,  sk2) TPSTEP(3,  sk1) TPSTEP(4,  sk3)
        TPSTEP(5,  sk1) TPSTEP(6,  sk2) TPSTEP(7,  sk1) TPSTEP(8,  sk4)
        TPSTEP(9,  sk1) TPSTEP(10, sk2) TPSTEP(11, sk1) TPSTEP(12, sk3)
        TPSTEP(13, sk1) TPSTEP(14, sk2) TPSTEP(15, sk1)
        #undef TPSTEP
        ((unsigned short*)(ws + WS_TPERM))[hb * 256 + tid] = (unsigned short)acc;
    } else {
        const int r = blockIdx.x - 512;          // 0..7, 16 row-groups each
        unsigned long long* tokp = (unsigned long long*)(ws + WS_TOKROW);
        for (int c = r * 16; c < r * 16 + 16; ++c) {
            int v = tokens[c * 256 + tid];       // s = c*4 + w, bit = lane (=b)
            unsigned long long m = __ballot(v != 0);
            if (lane == 0) tokp[c * 4 + w] = m;
        }
    }
}

// Plain inner loops, specialized by #r-type connections (see earlier rounds).
template<int NR>
__device__ __forceinline__ uint32_t parity_rows(
    const uint32_t* table, const unsigned short* AqL, const unsigned short* AkL,
    const unsigned short* ArL, int c, int hh, int lane,
    int p1, int k1, int p2, int k2)
{
    const int i = c * 64 + lane;
    const int aq = (int)AqL[i];
    uint32_t acc = 0;
    for (int sb = hh; sb < c; sb += 2) {
        int akv = (int)AkL[sb * 64 + lane];
        int dbase = i - sb * 64;                 // d >= 1 throughout
        #pragma unroll
        for (int jj = 0; jj < 64; ++jj) {
            int sak = __builtin_amdgcn_readlane(akv, jj);
            int d = dbase - jj;
            int ar;
            if (NR == 0)      ar = 0;
            else if (NR == 1) ar = ((d >> p1) & 1) << k1;
            else if (NR == 2) ar = (((d >> p1) & 1) << k1) | (((d >> p2) & 1) << k2);
            else              ar = (int)ArL[d];
            int addr = aq + sak + ar;
            acc ^= table[addr >> 5] >> (addr & 31);
        }
    }
    if (hh == (c & 1)) {
        int akv = (int)AkL[c * 64 + lane];
        #pragma unroll
        for (int jj = 0; jj < 64; ++jj) {
            int sak = __builtin_amdgcn_readlane(akv, jj);
            int d = lane - jj;
            int ar;
            if (NR == 0)      ar = 0;
            else if (NR == 1) ar = ((d >> p1) & 1) << k1;       // d<0 ok: masked below
            else if (NR == 2) ar = (((d >> p1) & 1) << k1)
                                 | (((d >> p2) & 1) << k2);
            else { int dm = d < 0 ? 0 : d; ar = (int)ArL[dm]; }
            int addr = aq + sak + ar;
            uint32_t bit = table[addr >> 5] >> (addr & 31);
            acc ^= (d >= 0) ? bit : 0u;
        }
    }
    return acc;
}

// Mask-method path for nr==0, 4<=nk<=7 blocks: a full j-sub-block's parity
// contribution to row i collapses to popcount-parity(Trow[qidx_i] & BOM_sb),
// since popcount-parity is additive under XOR we accumulate xacc ^= Trow&BOM.
// ~50x fewer ops than the 64-iteration plain loop; tails stay plain.
template<int NK>
__device__ __forceinline__ uint32_t mask_rows(
    const uint32_t* __restrict__ Tp, const uint32_t* __restrict__ table,
    const unsigned short* QidxL, const unsigned short* KidxL,
    const unsigned short* AqL, const unsigned short* AkL,
    uint32_t (*BOM)[4], int c, int hh, int w, int lane)
{
    constexpr int W = (NK <= 5) ? 1 : (1 << (NK - 5));   // u32 words per row
    // cooperative BOM build: wave w builds chunks 2w, 2w+1
    #pragma unroll
    for (int t = 0; t < 2; ++t) {
        int ch = w * 2 + t;
        int kj = (int)KidxL[ch * 64 + lane];
        uint32_t oh[W];
        #pragma unroll
        for (int u = 0; u < W; ++u)
            oh[u] = ((kj >> 5) == u) ? (1u << (kj & 31)) : 0u;
        #pragma unroll
        for (int off = 1; off < 64; off <<= 1) {
            #pragma unroll
            for (int u = 0; u < W; ++u)
                oh[u] ^= __shfl_xor(oh[u], off, 64);
        }
        if (lane == 0) {
            #pragma unroll
            for (int u = 0; u < W; ++u) BOM[ch][u] = oh[u];
        }
    }
    __syncthreads();
    const int i = c * 64 + lane;
    const int qidx = (int)QidxL[i];
    uint32_t Trow[W];
    if (NK == 4) {
        uint32_t word = Tp[qidx >> 1];
        Trow[0] = (qidx & 1) ? (word >> 16) : (word & 0xFFFFu);
    } else if (NK == 5) {
        Trow[0] = Tp[qidx];
    } else {
        #pragma unroll
        for (int u = 0; u < W; ++u)
            Trow[u] = Tp[(qidx << (NK - 5)) + u];
    }
    uint32_t xacc[W];
    #pragma unroll
    for (int u = 0; u < W; ++u) xacc[u] = 0;
    for (int sb = hh; sb < c; sb += 2) {
        #pragma unroll
        for (int u = 0; u < W; ++u) xacc[u] ^= Trow[u] & BOM[sb][u];
    }
    uint32_t xall = 0;
    #pragma unroll
    for (int u = 0; u < W; ++u) xall ^= xacc[u];
    uint32_t acc = (uint32_t)__popc(xall);       // parity lives in bit 0
    if (hh == (c & 1)) {                         // tail: plain loop
        const int aq = (int)AqL[i];
        int akv = (int)AkL[c * 64 + lane];
        #pragma unroll
        for (int jj = 0; jj < 64; ++jj) {
            int sak = __builtin_amdgcn_readlane(akv, jj);
            int addr = aq + sak;
            uint32_t bit = table[addr >> 5] >> (addr & 31);
            acc ^= (lane >= jj) ? bit : 0u;
        }
    }
    return acc;
}

// ---- Kernel 1: parity. 4 blocks per hb; block q owns chunks {q, 7-q} ----
__global__ __launch_bounds__(256) void softram_parity_kernel(
    const int* __restrict__ conn,     // (8, 64, 12)
    uint32_t* __restrict__ ws)
{
    __shared__ uint32_t table[128];
    __shared__ uint32_t Tp[128];
    __shared__ unsigned long long tokrow[512];
    __shared__ unsigned short AqL[512], AkL[512], ArL[512];
    __shared__ unsigned short QidxL[512], KidxL[512];
    __shared__ uint32_t BOM[8][4];
    __shared__ unsigned long long parbuf[4];

    const int tid  = threadIdx.x;
    const int lane = tid & 63;
    const int w    = tid >> 6;
    const int hb   = blockIdx.x >> 2;
    const int q    = blockIdx.x & 3;

    if (tid < 128) {
        table[tid] = ws[WS_TABLE + hb * 128 + tid];
        Tp[tid]    = ws[WS_TPERM + hb * 128 + tid];   // garbage if ineligible (unused)
    }
    {
        const unsigned long long* tokp = (const unsigned long long*)(ws + WS_TOKROW);
        tokrow[tid]       = tokp[tid];
        tokrow[tid + 256] = tokp[tid + 256];
    }
    __syncthreads();

    const int* cp = conn + hb * 12;
    int ck[12];
    #pragma unroll
    for (int k = 0; k < 12; ++k) ck[k] = cp[k];

    int nr = 0, nk = 0, p1 = 0, k1 = 0, p2 = 0, k2 = 0;
    #pragma unroll
    for (int k = 0; k < 12; ++k) {
        if (ck[k] >= 128) {
            if (nr == 0)      { p1 = ck[k] - 128; k1 = k; }
            else if (nr == 1) { p2 = ck[k] - 128; k2 = k; }
            ++nr;
        } else if (ck[k] >= 64) ++nk;
    }

    #pragma unroll
    for (int rep = 0; rep < 2; ++rep) {
        int s = tid + rep * 256;
        unsigned long long row = tokrow[s];
        int aq = 0, ak = 0, ar = 0, qidx = 0, kidx = 0, nqc = 0, nkc = 0;
        #pragma unroll
        for (int k = 0; k < 12; ++k) {
            int c = ck[k];                        // wave-uniform -> scalar branch
            if (c < 64) {
                int bit = (int)((row >> c) & 1ull);
                aq |= bit << k; qidx |= bit << nqc; ++nqc;
            } else if (c < 128) {
                int bit = (int)((row >> (c - 64)) & 1ull);
                ak |= bit << k; kidx |= bit << nkc; ++nkc;
            } else {
                ar |= ((s >> (c - 128)) & 1) << k;
            }
        }
        AqL[s] = (unsigned short)aq;
        AkL[s] = (unsigned short)ak;
        ArL[s] = (unsigned short)ar;
        QidxL[s] = (unsigned short)qidx;
        KidxL[s] = (unsigned short)kidx;
    }
    __syncthreads();

    const int c  = (w < 2) ? q : (7 - q);
    const int hh = w & 1;

    uint32_t acc;
    if (nr == 0 && nk >= 4 && nk <= 7) {
        if      (nk == 4) acc = mask_rows<4>(Tp, table, QidxL, KidxL, AqL, AkL, BOM, c, hh, w, lane);
        else if (nk == 5) acc = mask_rows<5>(Tp, table, QidxL, KidxL, AqL, AkL, BOM, c, hh, w, lane);
        else if (nk == 6) acc = mask_rows<6>(Tp, table, QidxL, KidxL, AqL, AkL, BOM, c, hh, w, lane);
        else              acc = mask_rows<7>(Tp, table, QidxL, KidxL, AqL, AkL, BOM, c, hh, w, lane);
    } else if (nr == 0) acc = parity_rows<0>(table, AqL, AkL, ArL, c, hh, lane, p1, k1, p2, k2);
    else if (nr == 1)   acc = parity_rows<1>(table, AqL, AkL, ArL, c, hh, lane, p1, k1, p2, k2);
    else if (nr == 2)   acc = parity_rows<2>(table, AqL, AkL, ArL, c, hh, lane, p1, k1, p2, k2);
    else                acc = parity_rows<3>(table, AqL, AkL, ArL, c, hh, lane, p1, k1, p2, k2);

    acc &= 1u;
    unsigned long long m = __ballot(acc != 0);
    if (lane == 0) parbuf[w] = m;
    __syncthreads();

    if (tid == 0) {
        unsigned long long m0 = parbuf[0] ^ parbuf[1];      // chunk q
        unsigned long long m1 = parbuf[2] ^ parbuf[3];      // chunk 7-q
        uint32_t* wp = ws + WS_PAR;
        wp[(hb * 8 + q) * 2]           = (uint32_t)m0;
        wp[(hb * 8 + q) * 2 + 1]       = (uint32_t)(m0 >> 32);
        wp[(hb * 8 + (7 - q)) * 2]     = (uint32_t)m1;
        wp[(hb * 8 + (7 - q)) * 2 + 1] = (uint32_t)(m1 >> 32);
    }
}

// ---- Kernel 2: majority vote over heads ----
__global__ __launch_bounds__(256) void softram_vote_kernel(
    const uint32_t* __restrict__ ws, float* __restrict__ out)
{
    int t = blockIdx.x * 256 + threadIdx.x;      // t = i*64 + b, 32768 total
    int b = t & 63;
    int i = t >> 6;
    const uint32_t* wp = ws + WS_PAR;
    int sum = 0;
    #pragma unroll
    for (int h = 0; h < 8; ++h) {
        int hb = h * 64 + b;
        uint32_t wv = wp[(hb * 8 + (i >> 6)) * 2 + ((i >> 5) & 1)];
        sum += (wv >> (i & 31)) & 1u;
    }
    out[t] = (sum > 4) ? 1.0f : 0.0f;            // THRESH = H/2 = 4
}

extern "C" void kernel_launch(void* const* d_in, const int* in_sizes, int n_in,
                              void* d_out, int out_size, void* d_ws, size_t ws_size,
                              hipStream_t stream) {
    const int*   tokens = (const int*)d_in[0];   // (512, 64)
    const int*   conn   = (const int*)d_in[1];   // (8, 64, 12)
    const float* ram    = (const float*)d_in[2]; // (8, 64, 4096)
    float*       out    = (float*)d_out;         // (512, 64)
    uint32_t*    ws     = (uint32_t*)d_ws;       // needs ~600 KB

    softram_pack_kernel<<<520, 256, 0, stream>>>(tokens, conn, ram, ws);
    softram_parity_kernel<<<2048, 256, 0, stream>>>(conn, ws);
    softram_vote_kernel<<<128, 256, 0, stream>>>(ws, out);
}

// Round 4
// 103.330 us; speedup vs baseline: 1.0014x; 1.0014x over previous
//
#include <hip/hip_runtime.h>
#include <stdint.h>

// S=512, B=64, H=8, K=12, P=9, L=137, T=4096, THRESH=4
// Workspace layout (u32 units):
//   [0, 65536)       packed ram tables: 128 u32 per hb (hb-major)   = 256 KB
//   [65536, 66560)   packed token rows: 512 u64                     = 4 KB
//   [66560, 74752)   parity bits: [hb][chunk(8)][2] u32             = 32 KB
#define WS_TABLE  0
#define WS_TOKROW 65536
#define WS_PAR    66560

// ---- Kernel 0: pack ram bits and token rows once into workspace ----
__global__ __launch_bounds__(256) void softram_pack_kernel(
    const int* __restrict__ tokens,   // (512, 64)
    const float* __restrict__ ram,    // (8, 64, 4096) values in {0,1}
    uint32_t* __restrict__ ws)
{
    const int tid = threadIdx.x, lane = tid & 63, w = tid >> 6;
    if (blockIdx.x < 512) {
        const int hb = blockIdx.x;
        const float* ramp = ram + (size_t)hb * 4096;
        uint32_t* tp = ws + WS_TABLE + hb * 128;
        #pragma unroll
        for (int c = 0; c < 16; ++c) {
            float v = ramp[c * 256 + tid];
            unsigned long long m = __ballot(v > 0.5f);
            if (lane == 0) {
                tp[c * 8 + w * 2]     = (uint32_t)m;
                tp[c * 8 + w * 2 + 1] = (uint32_t)(m >> 32);
            }
        }
    } else {
        const int r = blockIdx.x - 512;          // 0..7, 16 row-groups each
        unsigned long long* tokp = (unsigned long long*)(ws + WS_TOKROW);
        for (int c = r * 16; c < r * 16 + 16; ++c) {
            int v = tokens[c * 256 + tid];       // s = c*4 + w, bit = lane (=b)
            unsigned long long m = __ballot(v != 0);
            if (lane == 0) tokp[c * 4 + w] = m;
        }
    }
}

// Plain inner loops, specialized by #r-type connections.
// NR=0: ar==0. NR=1/2: ar from bits of d in VALU. NR>=3: ArL LDS read.
template<int NR>
__device__ __forceinline__ uint32_t parity_rows(
    const uint32_t* table, const unsigned short* AqL, const unsigned short* AkL,
    const unsigned short* ArL, int c, int hh, int lane,
    int p1, int k1, int p2, int k2)
{
    const int i = c * 64 + lane;
    const int aq = (int)AqL[i];
    uint32_t acc = 0;
    for (int sb = hh; sb < c; sb += 2) {
        int akv = (int)AkL[sb * 64 + lane];
        int dbase = i - sb * 64;                 // d >= 1 throughout
        #pragma unroll
        for (int jj = 0; jj < 64; ++jj) {
            int sak = __builtin_amdgcn_readlane(akv, jj);
            int d = dbase - jj;
            int ar;
            if (NR == 0)      ar = 0;
            else if (NR == 1) ar = ((d >> p1) & 1) << k1;
            else if (NR == 2) ar = (((d >> p1) & 1) << k1) | (((d >> p2) & 1) << k2);
            else              ar = (int)ArL[d];
            int addr = aq + sak + ar;
            acc ^= table[addr >> 5] >> (addr & 31);
        }
    }
    if (hh == (c & 1)) {
        int akv = (int)AkL[c * 64 + lane];
        #pragma unroll
        for (int jj = 0; jj < 64; ++jj) {
            int sak = __builtin_amdgcn_readlane(akv, jj);
            int d = lane - jj;
            int ar;
            if (NR == 0)      ar = 0;
            else if (NR == 1) ar = ((d >> p1) & 1) << k1;       // d<0 ok: masked below
            else if (NR == 2) ar = (((d >> p1) & 1) << k1)
                                 | (((d >> p2) & 1) << k2);
            else { int dm = d < 0 ? 0 : d; ar = (int)ArL[dm]; }
            int addr = aq + sak + ar;
            uint32_t bit = table[addr >> 5] >> (addr & 31);
            acc ^= (d >= 0) ? bit : 0u;
        }
    }
    return acc;
}

// ---- Kernel 1: parity. 4 blocks per hb; block q owns chunks {q, 7-q};
//      each chunk split across 2 waves by interleaved j-sub-blocks.
//      Mask path (nr==0, 4<=nk<=6, ~24% of blocks): full sub-block
//      contribution to row i collapses to parity(popc(Trow[qidx] & BOM_sb));
//      Tperm built in-kernel (8 blk/CU hides the Gray-walk latency),
//      W fixed at 2 words to bound VGPR pressure. ----
__global__ __launch_bounds__(256) void softram_parity_kernel(
    const int* __restrict__ conn,     // (8, 64, 12)
    uint32_t* __restrict__ ws)
{
    __shared__ uint32_t table[128];
    __shared__ uint32_t Tp[128];                 // permuted table (eligible only)
    __shared__ unsigned long long tokrow[512];
    __shared__ unsigned short AqL[512], AkL[512], ArL[512];
    __shared__ unsigned short QidxL[512], KidxL[512];
    __shared__ uint32_t BOM[8][2];
    __shared__ unsigned long long parbuf[4];

    const int tid  = threadIdx.x;
    const int lane = tid & 63;
    const int w    = tid >> 6;
    const int hb   = blockIdx.x >> 2;
    const int q    = blockIdx.x & 3;

    if (tid < 128) table[tid] = ws[WS_TABLE + hb * 128 + tid];
    {
        const unsigned long long* tokp = (const unsigned long long*)(ws + WS_TOKROW);
        tokrow[tid]       = tokp[tid];
        tokrow[tid + 256] = tokp[tid + 256];
    }
    __syncthreads();

    const int* cp = conn + hb * 12;
    int ck[12];
    #pragma unroll
    for (int k = 0; k < 12; ++k) ck[k] = cp[k];

    int nr = 0, nk = 0, p1 = 0, k1 = 0, p2 = 0, k2 = 0;
    #pragma unroll
    for (int k = 0; k < 12; ++k) {
        if (ck[k] >= 128) {
            if (nr == 0)      { p1 = ck[k] - 128; k1 = k; }
            else if (nr == 1) { p2 = ck[k] - 128; k2 = k; }
            ++nr;
        } else if (ck[k] >= 64) ++nk;
    }
    const bool eligible = (nr == 0 && nk >= 4 && nk <= 6);   // block-uniform

    // per-position partial addresses — identical to the r2 kernel
    #pragma unroll
    for (int rep = 0; rep < 2; ++rep) {
        int s = tid + rep * 256;
        unsigned long long row = tokrow[s];
        int aq = 0, ak = 0, ar = 0;
        #pragma unroll
        for (int k = 0; k < 12; ++k) {
            int c = ck[k];                        // wave-uniform -> scalar branch
            if (c < 64)       aq |= (int)((row >> c) & 1ull) << k;
            else if (c < 128) ak |= (int)((row >> (c - 64)) & 1ull) << k;
            else              ar |= ((s >> (c - 128)) & 1) << k;
        }
        AqL[s] = (unsigned short)aq;
        AkL[s] = (unsigned short)ak;
        ArL[s] = (unsigned short)ar;
    }
    __syncthreads();

    const int c  = (w < 2) ? q : (7 - q);
    const int hh = w & 1;
    uint32_t acc;

    if (eligible) {
        // compact q/k indices (eligible blocks only; re-derived from AqL/AkL)
        #pragma unroll
        for (int rep = 0; rep < 2; ++rep) {
            int s = tid + rep * 256;
            int aq = (int)AqL[s], ak = (int)AkL[s];
            int qidx = 0, kidx = 0, nqc = 0, nkc = 0;
            #pragma unroll
            for (int k = 0; k < 12; ++k) {
                if (ck[k] < 64) { qidx |= ((aq >> k) & 1) << nqc; ++nqc; }
                else            { kidx |= ((ak >> k) & 1) << nkc; ++nkc; }
            }
            QidxL[s] = (unsigned short)qidx;
            KidxL[s] = (unsigned short)kidx;
        }
        // cumulative scatter masks of the low-m kidx bits (m=1..4; nk>=4)
        uint32_t sk[4] = {0, 0, 0, 0};
        {
            int nkc = 0; uint32_t cur = 0;
            #pragma unroll
            for (int k = 0; k < 12; ++k) {
                if (ck[k] >= 64) {
                    if (nkc < 4) { cur |= 1u << k; sk[nkc] = cur; }
                    ++nkc;
                }
            }
        }
        // build permuted table: thread tid -> 16 consecutive linear bits
        // l = (qidx << nk) | kidx ; Gray walk flips low kidx bits only (nk>=4)
        {
            const int l0 = tid * 16;
            const int kidx0 = l0 & ((1 << nk) - 1);
            const int qidx0 = l0 >> nk;
            uint32_t a = 0;
            int nqc = 0, nkc = 0;
            #pragma unroll
            for (int k = 0; k < 12; ++k) {
                if (ck[k] < 64) { a |= (uint32_t)((qidx0 >> nqc) & 1) << k; ++nqc; }
                else            { a |= (uint32_t)((kidx0 >> nkc) & 1) << k; ++nkc; }
            }
            uint32_t bits = (table[a >> 5] >> (a & 31)) & 1u;
            #pragma unroll
            for (int o = 1; o < 16; ++o) {
                a ^= sk[__builtin_ctz((unsigned)o)];         // constant after unroll
                bits |= ((table[a >> 5] >> (a & 31)) & 1u) << o;
            }
            ((unsigned short*)Tp)[tid] = (unsigned short)bits;
        }
        __syncthreads();
        // BOM build: wave w builds chunks 2w, 2w+1 (odd-count one-hot XOR)
        #pragma unroll
        for (int t = 0; t < 2; ++t) {
            int ch = w * 2 + t;
            int kj = (int)KidxL[ch * 64 + lane];
            uint32_t oh0 = (kj < 32) ? (1u << kj) : 0u;
            uint32_t oh1 = (kj < 32) ? 0u : (1u << (kj - 32));
            #pragma unroll
            for (int off = 1; off < 64; off <<= 1) {
                oh0 ^= __shfl_xor(oh0, off, 64);
                oh1 ^= __shfl_xor(oh1, off, 64);
            }
            if (lane == 0) { BOM[ch][0] = oh0; BOM[ch][1] = oh1; }
        }
        __syncthreads();
        // row compute: xacc ^= Trow & BOM over owned full sub-blocks
        const int i = c * 64 + lane;
        const int qidx = (int)QidxL[i];
        uint32_t T0, T1;
        if (nk == 4)      { T0 = ((const unsigned short*)Tp)[qidx]; T1 = 0u; }
        else if (nk == 5) { T0 = Tp[qidx];                          T1 = 0u; }
        else              { T0 = Tp[qidx * 2]; T1 = Tp[qidx * 2 + 1]; }
        uint32_t x0 = 0, x1 = 0;
        for (int sb = hh; sb < c; sb += 2) {
            x0 ^= T0 & BOM[sb][0];
            x1 ^= T1 & BOM[sb][1];
        }
        acc = (uint32_t)__popc(x0 ^ x1);         // parity in bit 0
        // tail sub-block (j <= i masking): plain loop
        if (hh == (c & 1)) {
            const int aq = (int)AqL[i];
            int akv = (int)AkL[c * 64 + lane];
            #pragma unroll
            for (int jj = 0; jj < 64; ++jj) {
                int sak = __builtin_amdgcn_readlane(akv, jj);
                int addr = aq + sak;
                uint32_t bit = table[addr >> 5] >> (addr & 31);
                acc ^= (lane >= jj) ? bit : 0u;
            }
        }
    } else if (nr == 0) acc = parity_rows<0>(table, AqL, AkL, ArL, c, hh, lane, p1, k1, p2, k2);
    else if (nr == 1)   acc = parity_rows<1>(table, AqL, AkL, ArL, c, hh, lane, p1, k1, p2, k2);
    else if (nr == 2)   acc = parity_rows<2>(table, AqL, AkL, ArL, c, hh, lane, p1, k1, p2, k2);
    else                acc = parity_rows<3>(table, AqL, AkL, ArL, c, hh, lane, p1, k1, p2, k2);

    acc &= 1u;
    unsigned long long m = __ballot(acc != 0);
    if (lane == 0) parbuf[w] = m;
    __syncthreads();

    if (tid == 0) {
        unsigned long long m0 = parbuf[0] ^ parbuf[1];      // chunk q
        unsigned long long m1 = parbuf[2] ^ parbuf[3];      // chunk 7-q
        uint32_t* wp = ws + WS_PAR;
        wp[(hb * 8 + q) * 2]           = (uint32_t)m0;
        wp[(hb * 8 + q) * 2 + 1]       = (uint32_t)(m0 >> 32);
        wp[(hb * 8 + (7 - q)) * 2]     = (uint32_t)m1;
        wp[(hb * 8 + (7 - q)) * 2 + 1] = (uint32_t)(m1 >> 32);
    }
}

// ---- Kernel 2: majority vote over heads ----
__global__ __launch_bounds__(256) void softram_vote_kernel(
    const uint32_t* __restrict__ ws, float* __restrict__ out)
{
    int t = blockIdx.x * 256 + threadIdx.x;      // t = i*64 + b, 32768 total
    int b = t & 63;
    int i = t >> 6;
    const uint32_t* wp = ws + WS_PAR;
    int sum = 0;
    #pragma unroll
    for (int h = 0; h < 8; ++h) {
        int hb = h * 64 + b;
        uint32_t wv = wp[(hb * 8 + (i >> 6)) * 2 + ((i >> 5) & 1)];
        sum += (wv >> (i & 31)) & 1u;
    }
    out[t] = (sum > 4) ? 1.0f : 0.0f;            // THRESH = H/2 = 4
}

extern "C" void kernel_launch(void* const* d_in, const int* in_sizes, int n_in,
                              void* d_out, int out_size, void* d_ws, size_t ws_size,
                              hipStream_t stream) {
    const int*   tokens = (const int*)d_in[0];   // (512, 64)
    const int*   conn   = (const int*)d_in[1];   // (8, 64, 12)
    const float* ram    = (const float*)d_in[2]; // (8, 64, 4096)
    float*       out    = (float*)d_out;         // (512, 64)
    uint32_t*    ws     = (uint32_t*)d_ws;       // needs ~300 KB

    softram_pack_kernel<<<520, 256, 0, stream>>>(tokens, ram, ws);
    softram_parity_kernel<<<2048, 256, 0, stream>>>(conn, ws);
    softram_vote_kernel<<<128, 256, 0, stream>>>(ws, out);
}

// Round 5
// 101.513 us; speedup vs baseline: 1.0193x; 1.0179x over previous
//
#include <hip/hip_runtime.h>
#include <stdint.h>

// S=512, B=64, H=8, K=12, P=9, L=137, T=4096, THRESH=4
// Workspace layout (u32 units):
//   [0, 65536)       packed ram tables: 128 u32 per hb (hb-major)   = 256 KB
//   [65536, 66560)   packed token rows: 512 u64                     = 4 KB
//   [66560, 74752)   parity bits: [hb][chunk(8)][2] u32             = 32 KB
#define WS_TABLE  0
#define WS_TOKROW 65536
#define WS_PAR    66560

// ---- Kernel 0: pack ram bits and token rows once into workspace ----
__global__ __launch_bounds__(256) void softram_pack_kernel(
    const int* __restrict__ tokens,   // (512, 64)
    const float* __restrict__ ram,    // (8, 64, 4096) values in {0,1}
    uint32_t* __restrict__ ws)
{
    const int tid = threadIdx.x, lane = tid & 63, w = tid >> 6;
    if (blockIdx.x < 512) {
        const int hb = blockIdx.x;
        const float* ramp = ram + (size_t)hb * 4096;
        uint32_t* tp = ws + WS_TABLE + hb * 128;
        #pragma unroll
        for (int c = 0; c < 16; ++c) {
            float v = ramp[c * 256 + tid];
            unsigned long long m = __ballot(v > 0.5f);
            if (lane == 0) {
                tp[c * 8 + w * 2]     = (uint32_t)m;
                tp[c * 8 + w * 2 + 1] = (uint32_t)(m >> 32);
            }
        }
    } else {
        const int r = blockIdx.x - 512;          // 0..7, 16 row-groups each
        unsigned long long* tokp = (unsigned long long*)(ws + WS_TOKROW);
        for (int c = r * 16; c < r * 16 + 16; ++c) {
            int v = tokens[c * 256 + tid];       // s = c*4 + w, bit = lane (=b)
            unsigned long long m = __ballot(v != 0);
            if (lane == 0) tokp[c * 4 + w] = m;
        }
    }
}

// Inner parity loops, specialized by the number of r-type connections.
// NR=0: ar==0. NR=1/2: ar computed in VALU from bits of d (p*/k* are
// block-uniform -> SGPRs). NR>=3 (~4.5% of hb): fall back to the ArL LDS read.
// Rationale: the kernel is near-balanced on the VALU and LDS pipes; moving
// the Ar lookup to VALU for small nr trades 2 LDS clk for ~4 VALU clk.
// (Round 3/4 post-mortem: iteration-count cuts via the popcount-mask method
// were measured twice and cost ~+2us each — overhead > win. Do not re-add.)
template<int NR>
__device__ __forceinline__ uint32_t parity_rows(
    const uint32_t* table, const unsigned short* AqL, const unsigned short* AkL,
    const unsigned short* ArL, int c, int hh, int lane,
    int p1, int k1, int p2, int k2)
{
    const int i = c * 64 + lane;                 // this lane's output row
    const int aq = (int)AqL[i];
    uint32_t acc = 0;

    // full sub-blocks sb in [0, c), this wave takes sb ≡ hh (mod 2)
    for (int sb = hh; sb < c; sb += 2) {
        int akv = (int)AkL[sb * 64 + lane];
        int dbase = i - sb * 64;                 // d >= 1 throughout
        #pragma unroll
        for (int jj = 0; jj < 64; ++jj) {
            int sak = __builtin_amdgcn_readlane(akv, jj);   // wave-uniform Ak[j]
            int d = dbase - jj;
            int ar;
            if (NR == 0)      ar = 0;
            else if (NR == 1) ar = ((d >> p1) & 1) << k1;
            else if (NR == 2) ar = (((d >> p1) & 1) << k1) | (((d >> p2) & 1) << k2);
            else              ar = (int)ArL[d];
            int addr = aq + sak + ar;
            acc ^= table[addr >> 5] >> (addr & 31);         // parity in bit 0
        }
    }
    // tail sub-block sb == c (j <= i masking), owned by the matching-parity wave
    if (hh == (c & 1)) {
        int akv = (int)AkL[c * 64 + lane];
        #pragma unroll
        for (int jj = 0; jj < 64; ++jj) {
            int sak = __builtin_amdgcn_readlane(akv, jj);
            int d = lane - jj;
            int ar;
            if (NR == 0)      ar = 0;
            else if (NR == 1) ar = ((d >> p1) & 1) << k1;       // d<0 ok: bit masked below,
            else if (NR == 2) ar = (((d >> p1) & 1) << k1)      // addr stays < 4096 (disjoint bits)
                                 | (((d >> p2) & 1) << k2);
            else { int dm = d < 0 ? 0 : d; ar = (int)ArL[dm]; }
            int addr = aq + sak + ar;
            uint32_t bit = table[addr >> 5] >> (addr & 31);
            acc ^= (d >= 0) ? bit : 0u;
        }
    }
    return acc;
}

// ---- Kernel 1: parity. 4 blocks per hb; block q owns chunks {q, 7-q};
//      each chunk is split across 2 waves by interleaved j-sub-blocks. ----
__global__ __launch_bounds__(256) void softram_parity_kernel(
    const int* __restrict__ conn,     // (8, 64, 12)
    uint32_t* __restrict__ ws)
{
    __shared__ uint32_t table[128];
    __shared__ unsigned long long tokrow[512];
    __shared__ unsigned short AqL[512], AkL[512], ArL[512];
    __shared__ unsigned long long parbuf[4];

    const int tid  = threadIdx.x;
    const int lane = tid & 63;
    const int w    = tid >> 6;
    const int hb   = blockIdx.x >> 2;
    const int q    = blockIdx.x & 3;

    // stage packed table + token rows from workspace
    if (tid < 128) table[tid] = ws[WS_TABLE + hb * 128 + tid];
    {
        const unsigned long long* tokp = (const unsigned long long*)(ws + WS_TOKROW);
        tokrow[tid]       = tokp[tid];
        tokrow[tid + 256] = tokp[tid + 256];
    }
    __syncthreads();

    // per-position partial addresses (bits of addr are disjoint across q/k/r)
    const int* cp = conn + hb * 12;
    int ck[12];
    #pragma unroll
    for (int k = 0; k < 12; ++k) ck[k] = cp[k];

    // collect r-type connections (block-uniform)
    int nr = 0, p1 = 0, k1 = 0, p2 = 0, k2 = 0;
    #pragma unroll
    for (int k = 0; k < 12; ++k) {
        if (ck[k] >= 128) {
            if (nr == 0)      { p1 = ck[k] - 128; k1 = k; }
            else if (nr == 1) { p2 = ck[k] - 128; k2 = k; }
            ++nr;
        }
    }

    #pragma unroll
    for (int rep = 0; rep < 2; ++rep) {
        int s = tid + rep * 256;
        unsigned long long row = tokrow[s];
        int aq = 0, ak = 0, ar = 0;
        #pragma unroll
        for (int k = 0; k < 12; ++k) {
            int c = ck[k];                        // wave-uniform -> scalar branch
            if (c < 64)       aq |= (int)((row >> c) & 1ull) << k;
            else if (c < 128) ak |= (int)((row >> (c - 64)) & 1ull) << k;
            else              ar |= ((s >> (c - 128)) & 1) << k;
        }
        AqL[s] = (unsigned short)aq;
        AkL[s] = (unsigned short)ak;
        ArL[s] = (unsigned short)ar;
    }
    __syncthreads();

    // waves 0,1 -> chunk q (halves 0,1); waves 2,3 -> chunk 7-q (halves 0,1)
    const int c  = (w < 2) ? q : (7 - q);
    const int hh = w & 1;

    uint32_t acc;
    if (nr == 0)      acc = parity_rows<0>(table, AqL, AkL, ArL, c, hh, lane, p1, k1, p2, k2);
    else if (nr == 1) acc = parity_rows<1>(table, AqL, AkL, ArL, c, hh, lane, p1, k1, p2, k2);
    else if (nr == 2) acc = parity_rows<2>(table, AqL, AkL, ArL, c, hh, lane, p1, k1, p2, k2);
    else              acc = parity_rows<3>(table, AqL, AkL, ArL, c, hh, lane, p1, k1, p2, k2);

    acc &= 1u;
    unsigned long long m = __ballot(acc != 0);
    if (lane == 0) parbuf[w] = m;
    __syncthreads();

    if (tid == 0) {
        unsigned long long m0 = parbuf[0] ^ parbuf[1];      // chunk q
        unsigned long long m1 = parbuf[2] ^ parbuf[3];      // chunk 7-q
        uint32_t* wp = ws + WS_PAR;
        wp[(hb * 8 + q) * 2]           = (uint32_t)m0;
        wp[(hb * 8 + q) * 2 + 1]       = (uint32_t)(m0 >> 32);
        wp[(hb * 8 + (7 - q)) * 2]     = (uint32_t)m1;
        wp[(hb * 8 + (7 - q)) * 2 + 1] = (uint32_t)(m1 >> 32);
    }
}

// ---- Kernel 2: majority vote over heads ----
__global__ __launch_bounds__(256) void softram_vote_kernel(
    const uint32_t* __restrict__ ws, float* __restrict__ out)
{
    int t = blockIdx.x * 256 + threadIdx.x;      // t = i*64 + b, 32768 total
    int b = t & 63;
    int i = t >> 6;
    const uint32_t* wp = ws + WS_PAR;
    int sum = 0;
    #pragma unroll
    for (int h = 0; h < 8; ++h) {
        int hb = h * 64 + b;
        uint32_t wv = wp[(hb * 8 + (i >> 6)) * 2 + ((i >> 5) & 1)];
        sum += (wv >> (i & 31)) & 1u;
    }
    out[t] = (sum > 4) ? 1.0f : 0.0f;            // THRESH = H/2 = 4
}

extern "C" void kernel_launch(void* const* d_in, const int* in_sizes, int n_in,
                              void* d_out, int out_size, void* d_ws, size_t ws_size,
                              hipStream_t stream) {
    const int*   tokens = (const int*)d_in[0];   // (512, 64)
    const int*   conn   = (const int*)d_in[1];   // (8, 64, 12)
    const float* ram    = (const float*)d_in[2]; // (8, 64, 4096)
    float*       out    = (float*)d_out;         // (512, 64)
    uint32_t*    ws     = (uint32_t*)d_ws;       // needs ~300 KB

    softram_pack_kernel<<<520, 256, 0, stream>>>(tokens, ram, ws);
    softram_parity_kernel<<<2048, 256, 0, stream>>>(conn, ws);
    softram_vote_kernel<<<128, 256, 0, stream>>>(ws, out);
}